// Round 20
// baseline (435.569 us; speedup 1.0000x reference)
//
#include <hip/hip_runtime.h>
#include <hip/hip_bf16.h>

#define NNODES 50000
#define FDIM   512
#define HDIM   64
#define CDIM   20
#define NEDGE  1600000
#define NB     392          // padded bucket count; real buckets 0..390 (dst>>7)
#define SEB    16384        // edges per bhist/bscatter block
#define SBLK   98           // ceil(NEDGE/SEB)

typedef unsigned short ushort_t;
typedef __attribute__((ext_vector_type(8))) short bf16x8;
typedef __attribute__((ext_vector_type(4))) float f32x4;

static __device__ __forceinline__ ushort_t f2bf(float f) {
    __hip_bfloat16 h = __float2bfloat16(f);
    return *reinterpret_cast<ushort_t*>(&h);
}
static __device__ __forceinline__ bf16x8 pack_bf8(float4 v0, float4 v1) {
    bf16x8 r;
    r[0] = (short)f2bf(v0.x); r[1] = (short)f2bf(v0.y);
    r[2] = (short)f2bf(v0.z); r[3] = (short)f2bf(v0.w);
    r[4] = (short)f2bf(v1.x); r[5] = (short)f2bf(v1.y);
    r[6] = (short)f2bf(v1.z); r[7] = (short)f2bf(v1.w);
    return r;
}

// ---------------------------------------------------------------------------
// wt: transpose W1 pairs into Wt[type][col 0..127][k 0..511] bf16
__global__ __launch_bounds__(256) void wt_kernel(
    const float* __restrict__ W00, const float* __restrict__ W10,
    const float* __restrict__ W01, const float* __restrict__ W11,
    ushort_t* __restrict__ Wt0, ushort_t* __restrict__ Wt1)
{
    const int c    = blockIdx.x;          // 0..127
    const int type = blockIdx.y;          // 0..1
    const float* W;
    if (type == 0) W = (c < 64) ? W00 : W10;
    else           W = (c < 64) ? W01 : W11;
    const int cc = c & 63;
    ushort_t* Wt = type ? Wt1 : Wt0;
    #pragma unroll
    for (int kb = 0; kb < 2; ++kb) {
        int k = kb * 256 + threadIdx.x;
        Wt[c * 512 + k] = f2bf(W[k * 64 + cc]);
    }
}

// ---------------------------------------------------------------------------
// proj1 (MFMA, LDS-B): X[N][128] = feat[N][512] @ [Wa | Wb].
__global__ __launch_bounds__(256) void proj1_kernel(
    const float* __restrict__ f0, const float* __restrict__ f1,
    const ushort_t* __restrict__ Wt0, const ushort_t* __restrict__ Wt1,
    ushort_t* __restrict__ X0, ushort_t* __restrict__ X1)
{
    const float* feat; const ushort_t* Wt; ushort_t* X;
    if (blockIdx.y == 0) { feat = f0; Wt = Wt0; X = X0; }
    else                 { feat = f1; Wt = Wt1; X = X1; }

    __shared__ ushort_t Bs[128 * 512];   // 128 KB

    const int t    = threadIdx.x;
    const int wave = t >> 6;
    const int lane = t & 63;
    const int lrow = lane & 15;
    const int kgrp = lane >> 4;

    #pragma unroll 8
    for (int idx = t; idx < 128 * 64; idx += 256) {
        int c = idx >> 6;
        int s = idx & 63;
        bf16x8 v = *(const bf16x8*)(Wt + c * 512 + s * 8);
        *(bf16x8*)&Bs[c * 512 + ((s ^ (c & 7)) * 8)] = v;
    }
    __syncthreads();

    const int rowStrip = blockIdx.x * 128 + wave * 32;

    f32x4 acc[2][8];
    #pragma unroll
    for (int rt = 0; rt < 2; ++rt)
        #pragma unroll
        for (int ct = 0; ct < 8; ++ct)
            acc[rt][ct] = (f32x4){0.f, 0.f, 0.f, 0.f};

    long rA0 = rowStrip + lrow;       if (rA0 > NNODES - 1) rA0 = NNODES - 1;
    long rA1 = rowStrip + 16 + lrow;  if (rA1 > NNODES - 1) rA1 = NNODES - 1;
    const float* pA0 = feat + rA0 * FDIM + kgrp * 8;
    const float* pA1 = feat + rA1 * FDIM + kgrp * 8;

    #pragma unroll 4
    for (int k0 = 0; k0 < FDIM; k0 += 32) {
        float4 v0 = *(const float4*)(pA0 + k0);
        float4 v1 = *(const float4*)(pA0 + k0 + 4);
        float4 w0 = *(const float4*)(pA1 + k0);
        float4 w1 = *(const float4*)(pA1 + k0 + 4);
        bf16x8 a0 = pack_bf8(v0, v1);
        bf16x8 a1 = pack_bf8(w0, w1);
        const int sbase = (k0 >> 3) + kgrp;
        #pragma unroll
        for (int ct = 0; ct < 8; ++ct) {
            const int c = ct * 16 + lrow;
            bf16x8 b = *(const bf16x8*)&Bs[c * 512 + ((sbase ^ (c & 7)) * 8)];
            acc[0][ct] = __builtin_amdgcn_mfma_f32_16x16x32_bf16(a0, b, acc[0][ct], 0, 0, 0);
            acc[1][ct] = __builtin_amdgcn_mfma_f32_16x16x32_bf16(a1, b, acc[1][ct], 0, 0, 0);
        }
    }

    #pragma unroll
    for (int rt = 0; rt < 2; ++rt) {
        #pragma unroll
        for (int r = 0; r < 4; ++r) {
            int row = rowStrip + rt * 16 + kgrp * 4 + r;
            if (row < NNODES) {
                #pragma unroll
                for (int ct = 0; ct < 8; ++ct)
                    X[(long)row * 128 + ct * 16 + lrow] = f2bf(acc[rt][ct][r]);
            }
        }
    }
}

// ---------------------------------------------------------------------------
// bhist: per-relation bucket histogram; persists per-block counts.
__global__ __launch_bounds__(1024) void bhist_kernel(
    const int* __restrict__ e00, const int* __restrict__ e01,
    const int* __restrict__ e10, const int* __restrict__ e11,
    int* __restrict__ bcnt, int* __restrict__ blkcnt)
{
    int r = blockIdx.y;
    const int* e = (r == 0) ? e00 : (r == 1) ? e01 : (r == 2) ? e10 : e11;
    __shared__ int lc[NB];
    const int t = threadIdx.x;
    if (t < NB) lc[t] = 0;
    __syncthreads();
    const int e0 = blockIdx.x * SEB;
    #pragma unroll 4
    for (int k = 0; k < 16; ++k) {
        int i = e0 + t + k * 1024;
        if (i < NEDGE) atomicAdd(&lc[e[i] >> 7], 1);
    }
    __syncthreads();
    if (t < NB) {
        int c = lc[t];
        blkcnt[(r * NB + t) * SBLK + blockIdx.x] = c;
        if (c) atomicAdd(&bcnt[r * NB + t], c);
    }
}

// bscan: exclusive scan of bucket counts (1 block per relation) -> boff
__global__ __launch_bounds__(512) void bscan_kernel(
    const int* __restrict__ bcnt, int* __restrict__ boff)
{
    int r = blockIdx.x;
    __shared__ int s[512];
    const int t = threadIdx.x;
    int v = (t < NB) ? bcnt[r * NB + t] : 0;
    s[t] = v;
    __syncthreads();
    #pragma unroll
    for (int d = 1; d < 512; d <<= 1) {
        int add = (t >= d) ? s[t - d] : 0;
        __syncthreads();
        s[t] += add;
        __syncthreads();
    }
    if (t < NB) boff[r * NB + t] = s[t] - v;
}

// blkscan: per-(relation,bucket) prefix over blocks -> per-block cursors
__global__ __launch_bounds__(128) void blkscan_kernel(
    const int* __restrict__ boff, const int* __restrict__ blkcnt,
    int* __restrict__ blkbase)
{
    const int b = blockIdx.x;    // 0..NB-1
    const int r = blockIdx.y;
    const int t = threadIdx.x;   // 0..127
    __shared__ int s[128];
    int v = (t < SBLK) ? blkcnt[(r * NB + b) * SBLK + t] : 0;
    s[t] = v;
    __syncthreads();
    #pragma unroll
    for (int d = 1; d < 128; d <<= 1) {
        int add = (t >= d) ? s[t - d] : 0;
        __syncthreads();
        s[t] += add;
        __syncthreads();
    }
    if (t < SBLK) blkbase[(r * NB + b) * SBLK + t] = boff[r * NB + b] + s[t] - v;
}

// bscatter: single pass, precomputed cursors, 1024 threads, register-staged
// 16-edge batches (all loads issued before the atomic/store phase).
__global__ __launch_bounds__(1024) void bscatter_kernel(
    const int* __restrict__ e00, const int* __restrict__ e01,
    const int* __restrict__ e10, const int* __restrict__ e11,
    const float* __restrict__ v00, const float* __restrict__ v01,
    const float* __restrict__ v10, const float* __restrict__ v11,
    const int* __restrict__ blkbase, uint2* __restrict__ staged)
{
    int r = blockIdx.y;
    const int* e; const float* v;
    if      (r == 0) { e = e00; v = v00; }
    else if (r == 1) { e = e01; v = v01; }
    else if (r == 2) { e = e10; v = v10; }
    else             { e = e11; v = v11; }

    __shared__ int lcur[NB];
    const int t = threadIdx.x;
    if (t < NB) lcur[t] = blkbase[(r * NB + t) * SBLK + blockIdx.x];
    __syncthreads();
    const int e0 = blockIdx.x * SEB;
    uint2* st = staged + (long)r * NEDGE;

    int dst[16];
    int src[16];
    float val[16];
    #pragma unroll
    for (int k = 0; k < 16; ++k) {
        int i = e0 + t + k * 1024;
        bool ok = (i < NEDGE);
        dst[k] = ok ? e[i] : -1;
        src[k] = ok ? e[NEDGE + i] : 0;
        val[k] = ok ? v[i] : 0.f;
    }
    #pragma unroll
    for (int k = 0; k < 16; ++k) {
        if (dst[k] >= 0) {
            int pos = atomicAdd(&lcur[dst[k] >> 7], 1);
            st[pos] = make_uint2(((unsigned)dst[k] << 16) | (unsigned)src[k],
                                 __float_as_uint(val[k]));
        }
    }
}

// bfinal: per-bucket node-sort; 512 threads; packed 4B edata
// (src<<16 | bf16(val)).
__global__ __launch_bounds__(512) void bfinal_kernel(
    const int* __restrict__ boff, const int* __restrict__ bcnt,
    const uint2* __restrict__ staged,
    int* __restrict__ rowptr, unsigned* __restrict__ edata)
{
    const int b = blockIdx.x;
    const int r = blockIdx.y;
    const int t = threadIdx.x;
    const int s0  = boff[r * NB + b];
    const int cnt = bcnt[r * NB + b];
    const int e1  = s0 + cnt;
    const uint2* st = staged + (long)r * NEDGE;
    unsigned* ed = edata + (long)r * NEDGE;

    __shared__ int ncnt[128];
    __shared__ int sc[128];
    __shared__ int lcur[128];
    if (t < 128) ncnt[t] = 0;
    __syncthreads();
    for (int p = s0 + t; p < e1; p += 512)
        atomicAdd(&ncnt[(st[p].x >> 16) & 127], 1);
    __syncthreads();
    if (t < 128) sc[t] = ncnt[t];
    __syncthreads();
    #pragma unroll
    for (int d = 1; d < 128; d <<= 1) {
        int add = (t >= d && t < 128) ? sc[t - d] : 0;
        __syncthreads();
        if (t < 128) sc[t] += add;
        __syncthreads();
    }
    if (t < 128) {
        int excl = sc[t] - ncnt[t];
        int node = b * 128 + t;
        if (node <= NNODES) rowptr[r * (NNODES + 1) + node] = s0 + excl;
        lcur[t] = s0 + excl;
    }
    __syncthreads();
    for (int p = s0 + t; p < e1; p += 512) {
        uint2 w = st[p];
        int pos = atomicAdd(&lcur[(w.x >> 16) & 127], 1);
        ed[pos] = ((w.x & 0xffffu) << 16) | (unsigned)f2bf(__uint_as_float(w.y));
    }
}

// ---------------------------------------------------------------------------
// gather1 v4: wave per node; packed 4B edges; 4 edges per wave-step.
// Lane = (g = lane>>4 selects edge in quad, hq = lane&15 covers cols
// 4*hq..4*hq+3 via one dwordx2 load of 4 bf16). Halves VMEM instructions
// and address math per edge vs the dword variant.
#define G1_QUAD(U, acc0, acc1, acc2, acc3)                                   \
    {                                                                        \
        float vv_ = __uint_as_float((U) << 16);                              \
        uint2 x_ = *(const uint2*)&X[((U) >> 16) * 128u + colOff + hq * 4];  \
        acc0 = fmaf(vv_, __uint_as_float(x_.x << 16), acc0);                 \
        acc1 = fmaf(vv_, __uint_as_float(x_.x & 0xffff0000u), acc1);         \
        acc2 = fmaf(vv_, __uint_as_float(x_.y << 16), acc2);                 \
        acc3 = fmaf(vv_, __uint_as_float(x_.y & 0xffff0000u), acc3);         \
    }

__global__ __launch_bounds__(256) void gather1_kernel(
    const int* __restrict__ rowptr, const unsigned* __restrict__ edata,
    const ushort_t* __restrict__ X0, const ushort_t* __restrict__ X1,
    float* __restrict__ h0, float* __restrict__ h1)
{
    const int i    = blockIdx.y;
    const int lane = threadIdx.x & 63;
    const int node = __builtin_amdgcn_readfirstlane(blockIdx.x * 4 + (threadIdx.x >> 6));
    const int g    = lane >> 4;        // 0..3: edge within quad
    const int hq   = lane & 15;        // col group: cols 4*hq .. 4*hq+3
    const unsigned colOff = i * 64;

    float a0 = 0.f, a1 = 0.f, a2 = 0.f, a3 = 0.f;   // quad A chain
    float b0 = 0.f, b1 = 0.f, b2 = 0.f, b3 = 0.f;   // quad B chain

    #pragma unroll
    for (int j = 0; j < 2; ++j) {
        const int r = i * 2 + j;
        const int* rp = rowptr + r * (NNODES + 1);
        const unsigned* ed = edata + (long)r * NEDGE;
        const ushort_t* X = j ? X1 : X0;
        int s = __builtin_amdgcn_readfirstlane(rp[node]);
        int e = __builtin_amdgcn_readfirstlane(rp[node + 1]);
        int p = s;
        for (; p + 8 <= e; p += 8) {
            unsigned u0 = ed[p],     u1 = ed[p + 1], u2 = ed[p + 2], u3 = ed[p + 3];
            unsigned u4 = ed[p + 4], u5 = ed[p + 5], u6 = ed[p + 6], u7 = ed[p + 7];
            unsigned uA = (g == 0) ? u0 : (g == 1) ? u1 : (g == 2) ? u2 : u3;
            unsigned uB = (g == 0) ? u4 : (g == 1) ? u5 : (g == 2) ? u6 : u7;
            G1_QUAD(uA, a0, a1, a2, a3);
            G1_QUAD(uB, b0, b1, b2, b3);
        }
        if (p < e) {
            // masked final group; overread (<=28B) stays inside d_ws;
            // pad edges reuse edge-0's (valid) src with zero bf16 val.
            int rem = e - p;
            unsigned u0 = ed[p],     u1 = ed[p + 1], u2 = ed[p + 2], u3 = ed[p + 3];
            unsigned u4 = ed[p + 4], u5 = ed[p + 5], u6 = ed[p + 6], u7 = ed[p + 7];
            unsigned base = u0 & 0xffff0000u;
            unsigned z1 = (rem > 1) ? u1 : base;
            unsigned z2 = (rem > 2) ? u2 : base;
            unsigned z3 = (rem > 3) ? u3 : base;
            unsigned z4 = (rem > 4) ? u4 : base;
            unsigned z5 = (rem > 5) ? u5 : base;
            unsigned z6 = (rem > 6) ? u6 : base;
            unsigned z7 = base;
            (void)u7;
            unsigned uA = (g == 0) ? u0 : (g == 1) ? z1 : (g == 2) ? z2 : z3;
            unsigned uB = (g == 0) ? z4 : (g == 1) ? z5 : (g == 2) ? z6 : z7;
            G1_QUAD(uA, a0, a1, a2, a3);
            G1_QUAD(uB, b0, b1, b2, b3);
        }
    }
    float r0 = a0 + b0;
    float r1 = a1 + b1;
    float r2 = a2 + b2;
    float r3 = a3 + b3;
    r0 += __shfl_xor(r0, 16); r0 += __shfl_xor(r0, 32);
    r1 += __shfl_xor(r1, 16); r1 += __shfl_xor(r1, 32);
    r2 += __shfl_xor(r2, 16); r2 += __shfl_xor(r2, 32);
    r3 += __shfl_xor(r3, 16); r3 += __shfl_xor(r3, 32);
    if (lane < 16) {
        float* h = i ? h1 : h0;
        *(float4*)&h[node * 64 + hq * 4] = make_float4(r0, r1, r2, r3);
    }
}

// ---------------------------------------------------------------------------
// proj2: y[N][40] = relu(h[N][64]) @ [W2a | W2b]  (bf16 output)
__global__ __launch_bounds__(256) void proj2_kernel(
    const float* __restrict__ hacc, const float* __restrict__ W2a,
    const float* __restrict__ W2b, ushort_t* __restrict__ y)
{
    __shared__ float hs[32][65];
    __shared__ float ws[64][40];
    const int t = threadIdx.x;

    for (int p = t; p < 64 * 40; p += 256) {
        int k = p / 40, c = p % 40;
        ws[k][c] = (c < 20) ? W2a[k * 20 + c] : W2b[k * 20 + (c - 20)];
    }
    const int nodeBase = blockIdx.x * 32;
    for (int p = t; p < 32 * 64; p += 256) {
        int n = p >> 6, k = p & 63;
        float hv = 0.f;
        if (nodeBase + n < NNODES) hv = hacc[(long)(nodeBase + n) * HDIM + k];
        hs[n][k] = fmaxf(hv, 0.f);
    }
    __syncthreads();

    const int n  = t >> 3;
    const int cg = (t & 7) * 5;
    float acc[5] = {0.f, 0.f, 0.f, 0.f, 0.f};
    #pragma unroll 16
    for (int k = 0; k < 64; ++k) {
        float hv = hs[n][k];
        #pragma unroll
        for (int j = 0; j < 5; ++j) acc[j] = fmaf(hv, ws[k][cg + j], acc[j]);
    }
    if (nodeBase + n < NNODES) {
        #pragma unroll
        for (int j = 0; j < 5; ++j)
            y[(long)(nodeBase + n) * 40 + cg + j] = f2bf(acc[j]);
    }
}

// ---------------------------------------------------------------------------
// gather2: wave per node; packed 4B edges; 6 edges per gather instruction.
#define G2_SIX(U0,U1,U2,U3,U4,U5, ax, ay)                                    \
    {                                                                        \
        unsigned u_ = (g==0)?(U0):(g==1)?(U1):(g==2)?(U2):(g==3)?(U3):(g==4)?(U4):(U5); \
        float vv_ = __uint_as_float((u_ & 0xffffu) << 16);                   \
        unsigned y_ = *(const unsigned*)&y[(u_ >> 16) * 40u + colOff + c * 2]; \
        ax = fmaf(vv_, __uint_as_float(y_ << 16), ax);                       \
        ay = fmaf(vv_, __uint_as_float(y_ & 0xffff0000u), ay);               \
    }

__global__ __launch_bounds__(256) void gather2_kernel(
    const int* __restrict__ rowptr, const unsigned* __restrict__ edata,
    const ushort_t* __restrict__ y0, const ushort_t* __restrict__ y1,
    float* __restrict__ out)
{
    const int i    = blockIdx.y;
    const int lane = threadIdx.x & 63;
    const int node = __builtin_amdgcn_readfirstlane(blockIdx.x * 4 + (threadIdx.x >> 6));
    const int g = lane / 10;      // 0..5 (lanes 60..63 duplicate group 5; excluded in reduce)
    const int c = lane % 10;      // col pair (2c, 2c+1)
    const unsigned colOff = i * 20;

    float accA0 = 0.f, accA1 = 0.f, accB0 = 0.f, accB1 = 0.f;

    #pragma unroll
    for (int j = 0; j < 2; ++j) {
        const int r = i * 2 + j;
        const int* rp = rowptr + r * (NNODES + 1);
        const unsigned* ed = edata + (long)r * NEDGE;
        const ushort_t* y = j ? y1 : y0;
        int s = __builtin_amdgcn_readfirstlane(rp[node]);
        int e = __builtin_amdgcn_readfirstlane(rp[node + 1]);
        int p = s;
        for (; p + 12 <= e; p += 12) {
            unsigned u0 = ed[p],     u1 = ed[p + 1],  u2 = ed[p + 2];
            unsigned u3 = ed[p + 3], u4 = ed[p + 4],  u5 = ed[p + 5];
            unsigned x0 = ed[p + 6], x1 = ed[p + 7],  x2 = ed[p + 8];
            unsigned x3 = ed[p + 9], x4 = ed[p + 10], x5 = ed[p + 11];
            G2_SIX(u0, u1, u2, u3, u4, u5, accA0, accA1);
            G2_SIX(x0, x1, x2, x3, x4, x5, accB0, accB1);
        }
        for (; p + 6 <= e; p += 6) {
            unsigned u0 = ed[p],     u1 = ed[p + 1], u2 = ed[p + 2];
            unsigned u3 = ed[p + 3], u4 = ed[p + 4], u5 = ed[p + 5];
            G2_SIX(u0, u1, u2, u3, u4, u5, accA0, accA1);
        }
        if (p < e) {
            int rem = e - p;   // 1..5; overread (<=16B) stays in d_ws, masked
            unsigned u0 = ed[p],     u1 = ed[p + 1], u2 = ed[p + 2];
            unsigned u3 = ed[p + 3], u4 = ed[p + 4];
            unsigned base = u0 & 0xffff0000u;
            unsigned z1 = (rem > 1) ? u1 : base;
            unsigned z2 = (rem > 2) ? u2 : base;
            unsigned z3 = (rem > 3) ? u3 : base;
            unsigned z4 = (rem > 4) ? u4 : base;
            G2_SIX(u0, z1, z2, z3, z4, base, accA0, accA1);
        }
    }
    float u0 = (accA0 + accB0);
    float u1 = (accA1 + accB1);
    u0 += __shfl(u0, lane + 30);
    u1 += __shfl(u1, lane + 30);
    float q0 = u0 + __shfl(u0, lane + 10) + __shfl(u0, lane + 20);
    float q1 = u1 + __shfl(u1, lane + 10) + __shfl(u1, lane + 20);
    if (lane < 10)
        *(float2*)&out[i * (NNODES * CDIM) + node * CDIM + c * 2] = make_float2(q0, q1);
}

// ---------------------------------------------------------------------------
extern "C" void kernel_launch(void* const* d_in, const int* in_sizes, int n_in,
                              void* d_out, int out_size, void* d_ws, size_t ws_size,
                              hipStream_t stream) {
    const float* feat0 = (const float*)d_in[0];
    const float* feat1 = (const float*)d_in[1];
    const float* W1_00 = (const float*)d_in[2];
    const float* W1_01 = (const float*)d_in[3];
    const float* W1_10 = (const float*)d_in[4];
    const float* W1_11 = (const float*)d_in[5];
    const float* W2_00 = (const float*)d_in[6];
    const float* W2_01 = (const float*)d_in[7];
    const float* W2_10 = (const float*)d_in[8];
    const float* W2_11 = (const float*)d_in[9];
    const float* v00 = (const float*)d_in[10];
    const float* v01 = (const float*)d_in[11];
    const float* v10 = (const float*)d_in[12];
    const float* v11 = (const float*)d_in[13];
    const int* e00 = (const int*)d_in[14];
    const int* e01 = (const int*)d_in[15];
    const int* e10 = (const int*)d_in[16];
    const int* e11 = (const int*)d_in[17];

    // workspace layout (32-bit word offsets)
    unsigned* w = (unsigned*)d_ws;
    uint2*    staged  = (uint2*)w;                      // [0, 12.8M) words
    ushort_t* X0      = (ushort_t*)w;                   // alias staged (dead after bfinal)
    ushort_t* X1      = (ushort_t*)(w + 3200000);
    ushort_t* y0      = (ushort_t*)(w + 6400000);       // alias staged tail
    ushort_t* y1      = (ushort_t*)(w + 7400000);
    unsigned* edata   = (unsigned*)(w + 12800000);      // 6.4M words (packed 4B/edge)
    float*    h0      = (float*)(w + 19200000);         // 3.2M
    float*    h1      = (float*)(w + 22400000);         // 3.2M
    int*      rowptr  = (int*)(w + 25600000);           // 4*(NNODES+1)
    int*      bcnt    = (int*)(w + 25800004);           // 4*NB
    int*      boff    = (int*)(w + 25801572);           // 4*NB
    int*      blkcnt  = (int*)(w + 25803140);           // 4*NB*SBLK = 153664
    int*      blkbase = (int*)(w + 25956804);           // 153664
    ushort_t* Wt0     = (ushort_t*)(w + 26110468);      // 32768 words
    ushort_t* Wt1     = (ushort_t*)(w + 26143236);
    float*    out     = (float*)d_out;

    // weight transpose (independent of CSR build)
    wt_kernel<<<dim3(128, 2), 256, 0, stream>>>(W1_00, W1_10, W1_01, W1_11, Wt0, Wt1);

    // CSR build (bucketed, single-pass scatter via precomputed cursors)
    hipMemsetAsync(bcnt, 0, 4ull * NB * sizeof(int), stream);
    bhist_kernel<<<dim3(SBLK, 4), 1024, 0, stream>>>(e00, e01, e10, e11, bcnt, blkcnt);
    bscan_kernel<<<4, 512, 0, stream>>>(bcnt, boff);
    blkscan_kernel<<<dim3(NB, 4), 128, 0, stream>>>(boff, blkcnt, blkbase);
    bscatter_kernel<<<dim3(SBLK, 4), 1024, 0, stream>>>(
        e00, e01, e10, e11, v00, v01, v10, v11, blkbase, staged);
    bfinal_kernel<<<dim3(391, 4), 512, 0, stream>>>(boff, bcnt, staged, rowptr, edata);

    // layer-1 projections (MFMA, LDS-staged B; X overwrites dead staged)
    dim3 g1((NNODES + 127) / 128, 2);
    proj1_kernel<<<g1, 256, 0, stream>>>(feat0, feat1, Wt0, Wt1, X0, X1);

    // layer-1 aggregate
    gather1_kernel<<<dim3((NNODES + 3) / 4, 2), 256, 0, stream>>>(rowptr, edata, X0, X1, h0, h1);

    // layer-2 projections (bf16 y)
    proj2_kernel<<<(NNODES + 31) / 32, 256, 0, stream>>>(h0, W2_00, W2_10, y0);
    proj2_kernel<<<(NNODES + 31) / 32, 256, 0, stream>>>(h1, W2_01, W2_11, y1);

    // layer-2 aggregate
    gather2_kernel<<<dim3((NNODES + 3) / 4, 2), 256, 0, stream>>>(rowptr, edata, y0, y1, out);
}

// Round 21
// 430.958 us; speedup vs baseline: 1.0107x; 1.0107x over previous
//
#include <hip/hip_runtime.h>
#include <hip/hip_bf16.h>

#define NNODES 50000
#define FDIM   512
#define HDIM   64
#define CDIM   20
#define NEDGE  1600000
#define NB     392          // padded bucket count; real buckets 0..390 (dst>>7)
#define SEB    16384        // edges per bhist/bscatter block
#define SBLK   98           // ceil(NEDGE/SEB)

typedef unsigned short ushort_t;
typedef __attribute__((ext_vector_type(8))) short bf16x8;
typedef __attribute__((ext_vector_type(4))) float f32x4;

static __device__ __forceinline__ ushort_t f2bf(float f) {
    __hip_bfloat16 h = __float2bfloat16(f);
    return *reinterpret_cast<ushort_t*>(&h);
}
static __device__ __forceinline__ bf16x8 pack_bf8(float4 v0, float4 v1) {
    bf16x8 r;
    r[0] = (short)f2bf(v0.x); r[1] = (short)f2bf(v0.y);
    r[2] = (short)f2bf(v0.z); r[3] = (short)f2bf(v0.w);
    r[4] = (short)f2bf(v1.x); r[5] = (short)f2bf(v1.y);
    r[6] = (short)f2bf(v1.z); r[7] = (short)f2bf(v1.w);
    return r;
}

// ---------------------------------------------------------------------------
// wt: transpose W1 pairs into Wt[type][col 0..127][k 0..511] bf16
__global__ __launch_bounds__(256) void wt_kernel(
    const float* __restrict__ W00, const float* __restrict__ W10,
    const float* __restrict__ W01, const float* __restrict__ W11,
    ushort_t* __restrict__ Wt0, ushort_t* __restrict__ Wt1)
{
    const int c    = blockIdx.x;          // 0..127
    const int type = blockIdx.y;          // 0..1
    const float* W;
    if (type == 0) W = (c < 64) ? W00 : W10;
    else           W = (c < 64) ? W01 : W11;
    const int cc = c & 63;
    ushort_t* Wt = type ? Wt1 : Wt0;
    #pragma unroll
    for (int kb = 0; kb < 2; ++kb) {
        int k = kb * 256 + threadIdx.x;
        Wt[c * 512 + k] = f2bf(W[k * 64 + cc]);
    }
}

// ---------------------------------------------------------------------------
// proj1 (MFMA, LDS-B): X[N][128] = feat[N][512] @ [Wa | Wb].
__global__ __launch_bounds__(256) void proj1_kernel(
    const float* __restrict__ f0, const float* __restrict__ f1,
    const ushort_t* __restrict__ Wt0, const ushort_t* __restrict__ Wt1,
    ushort_t* __restrict__ X0, ushort_t* __restrict__ X1)
{
    const float* feat; const ushort_t* Wt; ushort_t* X;
    if (blockIdx.y == 0) { feat = f0; Wt = Wt0; X = X0; }
    else                 { feat = f1; Wt = Wt1; X = X1; }

    __shared__ ushort_t Bs[128 * 512];   // 128 KB

    const int t    = threadIdx.x;
    const int wave = t >> 6;
    const int lane = t & 63;
    const int lrow = lane & 15;
    const int kgrp = lane >> 4;

    #pragma unroll 8
    for (int idx = t; idx < 128 * 64; idx += 256) {
        int c = idx >> 6;
        int s = idx & 63;
        bf16x8 v = *(const bf16x8*)(Wt + c * 512 + s * 8);
        *(bf16x8*)&Bs[c * 512 + ((s ^ (c & 7)) * 8)] = v;
    }
    __syncthreads();

    const int rowStrip = blockIdx.x * 128 + wave * 32;

    f32x4 acc[2][8];
    #pragma unroll
    for (int rt = 0; rt < 2; ++rt)
        #pragma unroll
        for (int ct = 0; ct < 8; ++ct)
            acc[rt][ct] = (f32x4){0.f, 0.f, 0.f, 0.f};

    long rA0 = rowStrip + lrow;       if (rA0 > NNODES - 1) rA0 = NNODES - 1;
    long rA1 = rowStrip + 16 + lrow;  if (rA1 > NNODES - 1) rA1 = NNODES - 1;
    const float* pA0 = feat + rA0 * FDIM + kgrp * 8;
    const float* pA1 = feat + rA1 * FDIM + kgrp * 8;

    #pragma unroll 4
    for (int k0 = 0; k0 < FDIM; k0 += 32) {
        float4 v0 = *(const float4*)(pA0 + k0);
        float4 v1 = *(const float4*)(pA0 + k0 + 4);
        float4 w0 = *(const float4*)(pA1 + k0);
        float4 w1 = *(const float4*)(pA1 + k0 + 4);
        bf16x8 a0 = pack_bf8(v0, v1);
        bf16x8 a1 = pack_bf8(w0, w1);
        const int sbase = (k0 >> 3) + kgrp;
        #pragma unroll
        for (int ct = 0; ct < 8; ++ct) {
            const int c = ct * 16 + lrow;
            bf16x8 b = *(const bf16x8*)&Bs[c * 512 + ((sbase ^ (c & 7)) * 8)];
            acc[0][ct] = __builtin_amdgcn_mfma_f32_16x16x32_bf16(a0, b, acc[0][ct], 0, 0, 0);
            acc[1][ct] = __builtin_amdgcn_mfma_f32_16x16x32_bf16(a1, b, acc[1][ct], 0, 0, 0);
        }
    }

    #pragma unroll
    for (int rt = 0; rt < 2; ++rt) {
        #pragma unroll
        for (int r = 0; r < 4; ++r) {
            int row = rowStrip + rt * 16 + kgrp * 4 + r;
            if (row < NNODES) {
                #pragma unroll
                for (int ct = 0; ct < 8; ++ct)
                    X[(long)row * 128 + ct * 16 + lrow] = f2bf(acc[rt][ct][r]);
            }
        }
    }
}

// ---------------------------------------------------------------------------
// bhist: per-relation bucket histogram; persists per-block counts.
__global__ __launch_bounds__(1024) void bhist_kernel(
    const int* __restrict__ e00, const int* __restrict__ e01,
    const int* __restrict__ e10, const int* __restrict__ e11,
    int* __restrict__ bcnt, int* __restrict__ blkcnt)
{
    int r = blockIdx.y;
    const int* e = (r == 0) ? e00 : (r == 1) ? e01 : (r == 2) ? e10 : e11;
    __shared__ int lc[NB];
    const int t = threadIdx.x;
    if (t < NB) lc[t] = 0;
    __syncthreads();
    const int e0 = blockIdx.x * SEB;
    #pragma unroll 4
    for (int k = 0; k < 16; ++k) {
        int i = e0 + t + k * 1024;
        if (i < NEDGE) atomicAdd(&lc[e[i] >> 7], 1);
    }
    __syncthreads();
    if (t < NB) {
        int c = lc[t];
        blkcnt[(r * NB + t) * SBLK + blockIdx.x] = c;
        if (c) atomicAdd(&bcnt[r * NB + t], c);
    }
}

// bscan: exclusive scan of bucket counts (1 block per relation) -> boff
__global__ __launch_bounds__(512) void bscan_kernel(
    const int* __restrict__ bcnt, int* __restrict__ boff)
{
    int r = blockIdx.x;
    __shared__ int s[512];
    const int t = threadIdx.x;
    int v = (t < NB) ? bcnt[r * NB + t] : 0;
    s[t] = v;
    __syncthreads();
    #pragma unroll
    for (int d = 1; d < 512; d <<= 1) {
        int add = (t >= d) ? s[t - d] : 0;
        __syncthreads();
        s[t] += add;
        __syncthreads();
    }
    if (t < NB) boff[r * NB + t] = s[t] - v;
}

// blkscan: per-(relation,bucket) prefix over blocks -> per-block cursors
__global__ __launch_bounds__(128) void blkscan_kernel(
    const int* __restrict__ boff, const int* __restrict__ blkcnt,
    int* __restrict__ blkbase)
{
    const int b = blockIdx.x;    // 0..NB-1
    const int r = blockIdx.y;
    const int t = threadIdx.x;   // 0..127
    __shared__ int s[128];
    int v = (t < SBLK) ? blkcnt[(r * NB + b) * SBLK + t] : 0;
    s[t] = v;
    __syncthreads();
    #pragma unroll
    for (int d = 1; d < 128; d <<= 1) {
        int add = (t >= d) ? s[t - d] : 0;
        __syncthreads();
        s[t] += add;
        __syncthreads();
    }
    if (t < SBLK) blkbase[(r * NB + b) * SBLK + t] = boff[r * NB + b] + s[t] - v;
}

// bscatter: single pass, precomputed cursors, 1024 threads, register-staged
// 16-edge batches (all loads issued before the atomic/store phase).
__global__ __launch_bounds__(1024) void bscatter_kernel(
    const int* __restrict__ e00, const int* __restrict__ e01,
    const int* __restrict__ e10, const int* __restrict__ e11,
    const float* __restrict__ v00, const float* __restrict__ v01,
    const float* __restrict__ v10, const float* __restrict__ v11,
    const int* __restrict__ blkbase, uint2* __restrict__ staged)
{
    int r = blockIdx.y;
    const int* e; const float* v;
    if      (r == 0) { e = e00; v = v00; }
    else if (r == 1) { e = e01; v = v01; }
    else if (r == 2) { e = e10; v = v10; }
    else             { e = e11; v = v11; }

    __shared__ int lcur[NB];
    const int t = threadIdx.x;
    if (t < NB) lcur[t] = blkbase[(r * NB + t) * SBLK + blockIdx.x];
    __syncthreads();
    const int e0 = blockIdx.x * SEB;
    uint2* st = staged + (long)r * NEDGE;

    int dst[16];
    int src[16];
    float val[16];
    #pragma unroll
    for (int k = 0; k < 16; ++k) {
        int i = e0 + t + k * 1024;
        bool ok = (i < NEDGE);
        dst[k] = ok ? e[i] : -1;
        src[k] = ok ? e[NEDGE + i] : 0;
        val[k] = ok ? v[i] : 0.f;
    }
    #pragma unroll
    for (int k = 0; k < 16; ++k) {
        if (dst[k] >= 0) {
            int pos = atomicAdd(&lcur[dst[k] >> 7], 1);
            st[pos] = make_uint2(((unsigned)dst[k] << 16) | (unsigned)src[k],
                                 __float_as_uint(val[k]));
        }
    }
}

// bfinal: per-bucket node-sort; 512 threads; packed 4B edata
// (src<<16 | bf16(val)).
__global__ __launch_bounds__(512) void bfinal_kernel(
    const int* __restrict__ boff, const int* __restrict__ bcnt,
    const uint2* __restrict__ staged,
    int* __restrict__ rowptr, unsigned* __restrict__ edata)
{
    const int b = blockIdx.x;
    const int r = blockIdx.y;
    const int t = threadIdx.x;
    const int s0  = boff[r * NB + b];
    const int cnt = bcnt[r * NB + b];
    const int e1  = s0 + cnt;
    const uint2* st = staged + (long)r * NEDGE;
    unsigned* ed = edata + (long)r * NEDGE;

    __shared__ int ncnt[128];
    __shared__ int sc[128];
    __shared__ int lcur[128];
    if (t < 128) ncnt[t] = 0;
    __syncthreads();
    for (int p = s0 + t; p < e1; p += 512)
        atomicAdd(&ncnt[(st[p].x >> 16) & 127], 1);
    __syncthreads();
    if (t < 128) sc[t] = ncnt[t];
    __syncthreads();
    #pragma unroll
    for (int d = 1; d < 128; d <<= 1) {
        int add = (t >= d && t < 128) ? sc[t - d] : 0;
        __syncthreads();
        if (t < 128) sc[t] += add;
        __syncthreads();
    }
    if (t < 128) {
        int excl = sc[t] - ncnt[t];
        int node = b * 128 + t;
        if (node <= NNODES) rowptr[r * (NNODES + 1) + node] = s0 + excl;
        lcur[t] = s0 + excl;
    }
    __syncthreads();
    for (int p = s0 + t; p < e1; p += 512) {
        uint2 w = st[p];
        int pos = atomicAdd(&lcur[(w.x >> 16) & 127], 1);
        ed[pos] = ((w.x & 0xffffu) << 16) | (unsigned)f2bf(__uint_as_float(w.y));
    }
}

// ---------------------------------------------------------------------------
// gather1: wave per node; packed 4B edges; 2 edges per gather instruction.
#define G1_PAIR(uA, uB, ax, ay)                                              \
    {                                                                        \
        unsigned u_ = half ? (uB) : (uA);                                    \
        float vv_ = __uint_as_float((u_ & 0xffffu) << 16);                   \
        unsigned x_ = *(const unsigned*)&X[(u_ >> 16) * 128u + colOff + hl * 2]; \
        ax = fmaf(vv_, __uint_as_float(x_ << 16), ax);                       \
        ay = fmaf(vv_, __uint_as_float(x_ & 0xffff0000u), ay);               \
    }

__global__ __launch_bounds__(256) void gather1_kernel(
    const int* __restrict__ rowptr, const unsigned* __restrict__ edata,
    const ushort_t* __restrict__ X0, const ushort_t* __restrict__ X1,
    float* __restrict__ h0, float* __restrict__ h1)
{
    const int i    = blockIdx.y;
    const int lane = threadIdx.x & 63;
    const int node = __builtin_amdgcn_readfirstlane(blockIdx.x * 4 + (threadIdx.x >> 6));
    const int half = lane >> 5;
    const int hl   = lane & 31;
    const unsigned colOff = i * 64;

    float a0 = 0.f, a1 = 0.f, b0 = 0.f, b1 = 0.f;
    float c0 = 0.f, c1 = 0.f, d0 = 0.f, d1 = 0.f;

    #pragma unroll
    for (int j = 0; j < 2; ++j) {
        const int r = i * 2 + j;
        const int* rp = rowptr + r * (NNODES + 1);
        const unsigned* ed = edata + (long)r * NEDGE;
        const ushort_t* X = j ? X1 : X0;
        int s = __builtin_amdgcn_readfirstlane(rp[node]);
        int e = __builtin_amdgcn_readfirstlane(rp[node + 1]);
        int p = s;
        for (; p + 8 <= e; p += 8) {
            unsigned u0 = ed[p],     u1 = ed[p + 1], u2 = ed[p + 2], u3 = ed[p + 3];
            unsigned u4 = ed[p + 4], u5 = ed[p + 5], u6 = ed[p + 6], u7 = ed[p + 7];
            G1_PAIR(u0, u1, a0, a1);
            G1_PAIR(u2, u3, b0, b1);
            G1_PAIR(u4, u5, c0, c1);
            G1_PAIR(u6, u7, d0, d1);
        }
        if (p < e) {
            int rem = e - p;
            unsigned u0 = ed[p],     u1 = ed[p + 1], u2 = ed[p + 2], u3 = ed[p + 3];
            unsigned u4 = ed[p + 4], u5 = ed[p + 5], u6 = ed[p + 6], u7 = ed[p + 7];
            unsigned base = u0 & 0xffff0000u;
            unsigned z1 = (rem > 1) ? u1 : base;
            unsigned z2 = (rem > 2) ? u2 : base;
            unsigned z3 = (rem > 3) ? u3 : base;
            unsigned z4 = (rem > 4) ? u4 : base;
            unsigned z5 = (rem > 5) ? u5 : base;
            unsigned z6 = (rem > 6) ? u6 : base;
            unsigned z7 = (rem > 7) ? u7 : base;
            G1_PAIR(u0, z1, a0, a1);
            G1_PAIR(z2, z3, b0, b1);
            G1_PAIR(z4, z5, c0, c1);
            G1_PAIR(z6, z7, d0, d1);
        }
    }
    float r0 = (a0 + b0) + (c0 + d0);
    float r1 = (a1 + b1) + (c1 + d1);
    r0 += __shfl_xor(r0, 32);
    r1 += __shfl_xor(r1, 32);
    float* h = i ? h1 : h0;
    if (lane < 32)
        *(float2*)&h[node * 64 + hl * 2] = make_float2(r0, r1);
}

// ---------------------------------------------------------------------------
// proj2: y[N][40] = relu(h[N][64]) @ [W2a | W2b]  (bf16 output)
__global__ __launch_bounds__(256) void proj2_kernel(
    const float* __restrict__ hacc, const float* __restrict__ W2a,
    const float* __restrict__ W2b, ushort_t* __restrict__ y)
{
    __shared__ float hs[32][65];
    __shared__ float ws[64][40];
    const int t = threadIdx.x;

    for (int p = t; p < 64 * 40; p += 256) {
        int k = p / 40, c = p % 40;
        ws[k][c] = (c < 20) ? W2a[k * 20 + c] : W2b[k * 20 + (c - 20)];
    }
    const int nodeBase = blockIdx.x * 32;
    for (int p = t; p < 32 * 64; p += 256) {
        int n = p >> 6, k = p & 63;
        float hv = 0.f;
        if (nodeBase + n < NNODES) hv = hacc[(long)(nodeBase + n) * HDIM + k];
        hs[n][k] = fmaxf(hv, 0.f);
    }
    __syncthreads();

    const int n  = t >> 3;
    const int cg = (t & 7) * 5;
    float acc[5] = {0.f, 0.f, 0.f, 0.f, 0.f};
    #pragma unroll 16
    for (int k = 0; k < 64; ++k) {
        float hv = hs[n][k];
        #pragma unroll
        for (int j = 0; j < 5; ++j) acc[j] = fmaf(hv, ws[k][cg + j], acc[j]);
    }
    if (nodeBase + n < NNODES) {
        #pragma unroll
        for (int j = 0; j < 5; ++j)
            y[(long)(nodeBase + n) * 40 + cg + j] = f2bf(acc[j]);
    }
}

// ---------------------------------------------------------------------------
// gather2: wave per node; packed 4B edges; 6 edges per gather instruction.
#define G2_SIX(U0,U1,U2,U3,U4,U5, ax, ay)                                    \
    {                                                                        \
        unsigned u_ = (g==0)?(U0):(g==1)?(U1):(g==2)?(U2):(g==3)?(U3):(g==4)?(U4):(U5); \
        float vv_ = __uint_as_float((u_ & 0xffffu) << 16);                   \
        unsigned y_ = *(const unsigned*)&y[(u_ >> 16) * 40u + colOff + c * 2]; \
        ax = fmaf(vv_, __uint_as_float(y_ << 16), ax);                       \
        ay = fmaf(vv_, __uint_as_float(y_ & 0xffff0000u), ay);               \
    }

__global__ __launch_bounds__(256) void gather2_kernel(
    const int* __restrict__ rowptr, const unsigned* __restrict__ edata,
    const ushort_t* __restrict__ y0, const ushort_t* __restrict__ y1,
    float* __restrict__ out)
{
    const int i    = blockIdx.y;
    const int lane = threadIdx.x & 63;
    const int node = __builtin_amdgcn_readfirstlane(blockIdx.x * 4 + (threadIdx.x >> 6));
    const int g = lane / 10;      // 0..5 (lanes 60..63 duplicate group 5; excluded in reduce)
    const int c = lane % 10;      // col pair (2c, 2c+1)
    const unsigned colOff = i * 20;

    float accA0 = 0.f, accA1 = 0.f, accB0 = 0.f, accB1 = 0.f;

    #pragma unroll
    for (int j = 0; j < 2; ++j) {
        const int r = i * 2 + j;
        const int* rp = rowptr + r * (NNODES + 1);
        const unsigned* ed = edata + (long)r * NEDGE;
        const ushort_t* y = j ? y1 : y0;
        int s = __builtin_amdgcn_readfirstlane(rp[node]);
        int e = __builtin_amdgcn_readfirstlane(rp[node + 1]);
        int p = s;
        for (; p + 12 <= e; p += 12) {
            unsigned u0 = ed[p],     u1 = ed[p + 1],  u2 = ed[p + 2];
            unsigned u3 = ed[p + 3], u4 = ed[p + 4],  u5 = ed[p + 5];
            unsigned x0 = ed[p + 6], x1 = ed[p + 7],  x2 = ed[p + 8];
            unsigned x3 = ed[p + 9], x4 = ed[p + 10], x5 = ed[p + 11];
            G2_SIX(u0, u1, u2, u3, u4, u5, accA0, accA1);
            G2_SIX(x0, x1, x2, x3, x4, x5, accB0, accB1);
        }
        for (; p + 6 <= e; p += 6) {
            unsigned u0 = ed[p],     u1 = ed[p + 1], u2 = ed[p + 2];
            unsigned u3 = ed[p + 3], u4 = ed[p + 4], u5 = ed[p + 5];
            G2_SIX(u0, u1, u2, u3, u4, u5, accA0, accA1);
        }
        if (p < e) {
            int rem = e - p;   // 1..5; overread (<=16B) stays in d_ws, masked
            unsigned u0 = ed[p],     u1 = ed[p + 1], u2 = ed[p + 2];
            unsigned u3 = ed[p + 3], u4 = ed[p + 4];
            unsigned base = u0 & 0xffff0000u;
            unsigned z1 = (rem > 1) ? u1 : base;
            unsigned z2 = (rem > 2) ? u2 : base;
            unsigned z3 = (rem > 3) ? u3 : base;
            unsigned z4 = (rem > 4) ? u4 : base;
            G2_SIX(u0, z1, z2, z3, z4, base, accA0, accA1);
        }
    }
    float u0 = (accA0 + accB0);
    float u1 = (accA1 + accB1);
    u0 += __shfl(u0, lane + 30);
    u1 += __shfl(u1, lane + 30);
    float q0 = u0 + __shfl(u0, lane + 10) + __shfl(u0, lane + 20);
    float q1 = u1 + __shfl(u1, lane + 10) + __shfl(u1, lane + 20);
    if (lane < 10)
        *(float2*)&out[i * (NNODES * CDIM) + node * CDIM + c * 2] = make_float2(q0, q1);
}

// ---------------------------------------------------------------------------
extern "C" void kernel_launch(void* const* d_in, const int* in_sizes, int n_in,
                              void* d_out, int out_size, void* d_ws, size_t ws_size,
                              hipStream_t stream) {
    const float* feat0 = (const float*)d_in[0];
    const float* feat1 = (const float*)d_in[1];
    const float* W1_00 = (const float*)d_in[2];
    const float* W1_01 = (const float*)d_in[3];
    const float* W1_10 = (const float*)d_in[4];
    const float* W1_11 = (const float*)d_in[5];
    const float* W2_00 = (const float*)d_in[6];
    const float* W2_01 = (const float*)d_in[7];
    const float* W2_10 = (const float*)d_in[8];
    const float* W2_11 = (const float*)d_in[9];
    const float* v00 = (const float*)d_in[10];
    const float* v01 = (const float*)d_in[11];
    const float* v10 = (const float*)d_in[12];
    const float* v11 = (const float*)d_in[13];
    const int* e00 = (const int*)d_in[14];
    const int* e01 = (const int*)d_in[15];
    const int* e10 = (const int*)d_in[16];
    const int* e11 = (const int*)d_in[17];

    // workspace layout (32-bit word offsets)
    unsigned* w = (unsigned*)d_ws;
    uint2*    staged  = (uint2*)w;                      // [0, 12.8M) words
    ushort_t* X0      = (ushort_t*)w;                   // alias staged (dead after bfinal)
    ushort_t* X1      = (ushort_t*)(w + 3200000);
    ushort_t* y0      = (ushort_t*)(w + 6400000);       // alias staged tail
    ushort_t* y1      = (ushort_t*)(w + 7400000);
    unsigned* edata   = (unsigned*)(w + 12800000);      // 6.4M words (packed 4B/edge)
    float*    h0      = (float*)(w + 19200000);         // 3.2M
    float*    h1      = (float*)(w + 22400000);         // 3.2M
    int*      rowptr  = (int*)(w + 25600000);           // 4*(NNODES+1)
    int*      bcnt    = (int*)(w + 25800004);           // 4*NB
    int*      boff    = (int*)(w + 25801572);           // 4*NB
    int*      blkcnt  = (int*)(w + 25803140);           // 4*NB*SBLK = 153664
    int*      blkbase = (int*)(w + 25956804);           // 153664
    ushort_t* Wt0     = (ushort_t*)(w + 26110468);      // 32768 words
    ushort_t* Wt1     = (ushort_t*)(w + 26143236);
    float*    out     = (float*)d_out;

    // weight transpose (independent of CSR build)
    wt_kernel<<<dim3(128, 2), 256, 0, stream>>>(W1_00, W1_10, W1_01, W1_11, Wt0, Wt1);

    // CSR build (bucketed, single-pass scatter via precomputed cursors)
    hipMemsetAsync(bcnt, 0, 4ull * NB * sizeof(int), stream);
    bhist_kernel<<<dim3(SBLK, 4), 1024, 0, stream>>>(e00, e01, e10, e11, bcnt, blkcnt);
    bscan_kernel<<<4, 512, 0, stream>>>(bcnt, boff);
    blkscan_kernel<<<dim3(NB, 4), 128, 0, stream>>>(boff, blkcnt, blkbase);
    bscatter_kernel<<<dim3(SBLK, 4), 1024, 0, stream>>>(
        e00, e01, e10, e11, v00, v01, v10, v11, blkbase, staged);
    bfinal_kernel<<<dim3(391, 4), 512, 0, stream>>>(boff, bcnt, staged, rowptr, edata);

    // layer-1 projections (MFMA, LDS-staged B; X overwrites dead staged)
    dim3 g1((NNODES + 127) / 128, 2);
    proj1_kernel<<<g1, 256, 0, stream>>>(feat0, feat1, Wt0, Wt1, X0, X1);

    // layer-1 aggregate
    gather1_kernel<<<dim3((NNODES + 3) / 4, 2), 256, 0, stream>>>(rowptr, edata, X0, X1, h0, h1);

    // layer-2 projections (bf16 y)
    proj2_kernel<<<(NNODES + 31) / 32, 256, 0, stream>>>(h0, W2_00, W2_10, y0);
    proj2_kernel<<<(NNODES + 31) / 32, 256, 0, stream>>>(h1, W2_01, W2_11, y1);

    // layer-2 aggregate
    gather2_kernel<<<dim3((NNODES + 3) / 4, 2), 256, 0, stream>>>(rowptr, edata, y0, y1, out);
}